// Round 1
// baseline (537.382 us; speedup 1.0000x reference)
//
#include <hip/hip_runtime.h>
#include <math.h>

#define NS 4096
#define NC 500
#define NF 256
#define NK 400
#define KC_GEMM 8      // K chunks for gemm split (512 rows each)
#define KC_CS   32     // K chunks for colsum (128 rows each)

// ---------------- kernel 1: masked queue reduction ----------------
// one wave per (c,f) row of 400 floats; masked sum over k < queue_size[c]
__global__ void k_queue_reduce(const float* __restrict__ queue,
                               const int* __restrict__ qsize,
                               float* __restrict__ qsum) {
  int wave = (blockIdx.x * blockDim.x + threadIdx.x) >> 6;
  int lane = threadIdx.x & 63;
  if (wave >= NC * NF) return;
  int c = wave >> 8;                    // NF = 256
  int qs = qsize[c];
  const float* base = queue + (size_t)wave * NK;
  float s = 0.f;
  {
    int k = 4 * lane;                   // 0..255
    float4 v = *reinterpret_cast<const float4*>(base + k);
    if (k + 0 < qs) s += v.x;
    if (k + 1 < qs) s += v.y;
    if (k + 2 < qs) s += v.z;
    if (k + 3 < qs) s += v.w;
  }
  if (lane < 36) {
    int k = 256 + 4 * lane;             // 256..399
    float4 v = *reinterpret_cast<const float4*>(base + k);
    if (k + 0 < qs) s += v.x;
    if (k + 1 < qs) s += v.y;
    if (k + 2 < qs) s += v.z;
    if (k + 3 < qs) s += v.w;
  }
  #pragma unroll
  for (int m = 32; m; m >>= 1) s += __shfl_xor(s, m);
  if (lane == 0) qsum[wave] = s;
}

// ---------------- kernel 2: split-K GEMM partials  P[kc][c][f] = sum_n Y[n,c]*X[n,f]
__global__ void k_gemm_partial(const float* __restrict__ X,
                               const float* __restrict__ Y,
                               float* __restrict__ P) {
  const int f  = threadIdx.x;           // 0..255 = feature
  const int c0 = blockIdx.x * 16;       // class tile
  const int kc = blockIdx.y;
  const int n0 = kc * (NS / KC_GEMM);
  float acc[16];
  #pragma unroll
  for (int j = 0; j < 16; ++j) acc[j] = 0.f;

  if (c0 + 16 <= NC) {
    #pragma unroll 2
    for (int n = n0; n < n0 + NS / KC_GEMM; ++n) {
      float xv = X[(size_t)n * NF + f];
      const float* yr = Y + (size_t)n * NC + c0;   // wave-uniform -> s_load
      #pragma unroll
      for (int j = 0; j < 16; ++j) acc[j] = fmaf(yr[j], xv, acc[j]);
    }
  } else {
    for (int n = n0; n < n0 + NS / KC_GEMM; ++n) {
      float xv = X[(size_t)n * NF + f];
      const float* yr = Y + (size_t)n * NC + c0;
      #pragma unroll
      for (int j = 0; j < 16; ++j)
        if (c0 + j < NC) acc[j] = fmaf(yr[j], xv, acc[j]);
    }
  }
  #pragma unroll
  for (int j = 0; j < 16; ++j)
    if (c0 + j < NC) P[((size_t)kc * NC + c0 + j) * NF + f] = acc[j];
}

// ---------------- kernel 3: column-sum partials  CS[kc][c] = sum_{n in chunk} Y[n,c]
__global__ void k_colsum(const float* __restrict__ Y, float* __restrict__ CS) {
  int c  = threadIdx.x;                 // 512 threads
  int kc = blockIdx.x;                  // 32 chunks of 128 rows
  float s = 0.f;
  if (c < NC) {
    int n0 = kc * (NS / KC_CS);
    for (int n = n0; n < n0 + NS / KC_CS; ++n) s += Y[(size_t)n * NC + c];
  }
  CS[kc * 512 + c] = s;
}

// ---------------- kernel 4: finalize means ----------------
__global__ void k_means(const float* __restrict__ qsum,
                        const int* __restrict__ qsize,
                        const float* __restrict__ Psrc,
                        const float* __restrict__ Ptgt,
                        const float* __restrict__ CSsrc,
                        const float* __restrict__ CStgt,
                        float* __restrict__ MS, float* __restrict__ MT) {
  int c = blockIdx.x, f = threadIdx.x;
  float cs_s = 0.f, cs_t = 0.f;
  #pragma unroll
  for (int kc = 0; kc < KC_CS; ++kc) {
    cs_s += CSsrc[kc * 512 + c];
    cs_t += CStgt[kc * 512 + c];
  }
  float num = (float)qsize[c];
  float ns = qsum[(size_t)c * NF + f];
  float nt = 0.f;
  #pragma unroll
  for (int kc = 0; kc < KC_GEMM; ++kc) {
    ns += Psrc[((size_t)kc * NC + c) * NF + f];
    nt += Ptgt[((size_t)kc * NC + c) * NF + f];
  }
  MS[(size_t)c * NF + f] = ns / (num + cs_s + 1e-8f);
  MT[(size_t)c * NF + f] = nt / (cs_t + 1e-8f);
}

// ---------------- kernel 5: distances ----------------
__global__ void k_dist(const float* __restrict__ MS, const float* __restrict__ MT,
                       float* __restrict__ ipart, float* __restrict__ epart) {
  int c1 = blockIdx.x, f = threadIdx.x;  // 256 threads
  __shared__ float a[NF];
  __shared__ float red[8];
  float av = MS[(size_t)c1 * NF + f];
  a[f] = av;
  float d = av - MT[(size_t)c1 * NF + f];
  float s = d * d;
  #pragma unroll
  for (int m = 32; m; m >>= 1) s += __shfl_xor(s, m);
  int wid = f >> 6, lane = f & 63;
  if (lane == 0) red[wid] = s;
  __syncthreads();
  if (f == 0) ipart[c1] = sqrtf(fmaxf(red[0] + red[1] + red[2] + red[3], 1e-12f));

  float wsum = 0.f;
  for (int c2 = wid; c2 < NC; c2 += 4) {
    float t = 0.f;
    #pragma unroll
    for (int j = 0; j < 4; ++j) {
      int ff = lane + 64 * j;
      float dd = a[ff] - MS[(size_t)c2 * NF + ff];
      t = fmaf(dd, dd, t);
    }
    #pragma unroll
    for (int m = 32; m; m >>= 1) t += __shfl_xor(t, m);
    if (lane == 0) wsum += sqrtf(fmaxf(t, 1e-12f));
  }
  if (lane == 0) red[4 + wid] = wsum;
  __syncthreads();
  if (f == 0) epart[c1] = red[4] + red[5] + red[6] + red[7];
}

// ---------------- kernel 6: final scalars ----------------
__global__ void k_final(const float* __restrict__ ipart,
                        const float* __restrict__ epart,
                        float* __restrict__ out) {
  int t = threadIdx.x;                  // 512 threads
  float si = 0.f, se = 0.f;
  if (t < NC) { si = ipart[t]; se = epart[t]; }
  #pragma unroll
  for (int m = 32; m; m >>= 1) { si += __shfl_xor(si, m); se += __shfl_xor(se, m); }
  __shared__ float ri[8], re[8];
  int wid = t >> 6, lane = t & 63;
  if (lane == 0) { ri[wid] = si; re[wid] = se; }
  __syncthreads();
  if (t == 0) {
    float A = 0.f, B = 0.f;
    #pragma unroll
    for (int w = 0; w < 8; ++w) { A += ri[w]; B += re[w]; }
    out[0] = A / (float)NC;
    out[1] = B / ((float)NC * (float)NC);
  }
}

extern "C" void kernel_launch(void* const* d_in, const int* in_sizes, int n_in,
                              void* d_out, int out_size, void* d_ws, size_t ws_size,
                              hipStream_t stream) {
  const float* src_x = (const float*)d_in[0];
  const float* tgt_x = (const float*)d_in[1];
  const float* src_y = (const float*)d_in[2];
  const float* tgt_y = (const float*)d_in[3];
  const float* queue = (const float*)d_in[4];
  const int*   qsize = (const int*)d_in[5];
  float* out = (float*)d_out;

  float* ws   = (float*)d_ws;
  float* qsum = ws;                                   // 128000
  float* P    = qsum + NC * NF;                       // 2 * 8 * 128000
  float* Psrc = P;
  float* Ptgt = P + (size_t)KC_GEMM * NC * NF;
  float* CS   = Ptgt + (size_t)KC_GEMM * NC * NF;     // 2 * 32 * 512
  float* CSs  = CS;
  float* CSt  = CS + KC_CS * 512;
  float* MS   = CSt + KC_CS * 512;                    // 128000
  float* MT   = MS + NC * NF;                         // 128000
  float* ipart = MT + NC * NF;                        // 500
  float* epart = ipart + NC;                          // 500

  // 1) queue masked sums: 128000 waves, 4 waves/block
  k_queue_reduce<<<(NC * NF) / 4, 256, 0, stream>>>(queue, qsize, qsum);

  // 2) GEMM partials (deterministic split-K)
  dim3 g2((NC + 15) / 16, KC_GEMM);
  k_gemm_partial<<<g2, 256, 0, stream>>>(src_x, src_y, Psrc);
  k_gemm_partial<<<g2, 256, 0, stream>>>(tgt_x, tgt_y, Ptgt);

  // 3) column sums
  k_colsum<<<KC_CS, 512, 0, stream>>>(src_y, CSs);
  k_colsum<<<KC_CS, 512, 0, stream>>>(tgt_y, CSt);

  // 4) means
  k_means<<<NC, NF, 0, stream>>>(qsum, qsize, Psrc, Ptgt, CSs, CSt, MS, MT);

  // 5) distances
  k_dist<<<NC, NF, 0, stream>>>(MS, MT, ipart, epart);

  // 6) final reduction
  k_final<<<1, 512, 0, stream>>>(ipart, epart, out);
}

// Round 2
// 166.401 us; speedup vs baseline: 3.2294x; 3.2294x over previous
//
#include <hip/hip_runtime.h>
#include <math.h>

#define NS 4096
#define NC 500
#define NF 256
#define NK 400
#define KC_GEMM 16     // K chunks for gemm split (256 rows each)
#define KC_CS   32     // K chunks for colsum (128 rows each)

// ---------------- kernel 1: masked queue reduction ----------------
// one wave per (c,f) row of 400 floats; masked sum over k < queue_size[c]
__global__ void k_queue_reduce(const float* __restrict__ queue,
                               const int* __restrict__ qsize,
                               float* __restrict__ qsum) {
  int wave = (blockIdx.x * blockDim.x + threadIdx.x) >> 6;
  int lane = threadIdx.x & 63;
  if (wave >= NC * NF) return;
  int c = wave >> 8;                    // NF = 256
  int qs = qsize[c];
  const float* base = queue + (size_t)wave * NK;
  float s = 0.f;
  {
    int k = 4 * lane;                   // 0..255
    float4 v = *reinterpret_cast<const float4*>(base + k);
    if (k + 0 < qs) s += v.x;
    if (k + 1 < qs) s += v.y;
    if (k + 2 < qs) s += v.z;
    if (k + 3 < qs) s += v.w;
  }
  if (lane < 36) {
    int k = 256 + 4 * lane;             // 256..399
    float4 v = *reinterpret_cast<const float4*>(base + k);
    if (k + 0 < qs) s += v.x;
    if (k + 1 < qs) s += v.y;
    if (k + 2 < qs) s += v.z;
    if (k + 3 < qs) s += v.w;
  }
  #pragma unroll
  for (int m = 32; m; m >>= 1) s += __shfl_xor(s, m);
  if (lane == 0) qsum[wave] = s;
}

// ---------------- kernel 2: split-K GEMM partials ----------------
// P[kc][c][f] = sum_{n in chunk kc} Y[n,c] * X[n,f]
// blockIdx: x = class tile (16 classes), y = K chunk, z = 0:src 1:tgt
// Y tile staged in LDS (256 rows x 16 cols = 16 KB); X loads coalesced.
__global__ void k_gemm_partial(const float* __restrict__ Xs,
                               const float* __restrict__ Ys,
                               float* __restrict__ Ps,
                               const float* __restrict__ Xt,
                               const float* __restrict__ Yt,
                               float* __restrict__ Pt) {
  const float* X = blockIdx.z ? Xt : Xs;
  const float* Y = blockIdx.z ? Yt : Ys;
  float*       P = blockIdx.z ? Pt : Ps;

  __shared__ float ytile[NS / KC_GEMM][16];     // 256 x 16 = 16 KB
  const int f  = threadIdx.x;                   // 0..255 = feature
  const int c0 = blockIdx.x * 16;               // class tile
  const int kc = blockIdx.y;
  const int n0 = kc * (NS / KC_GEMM);
  const int cmax = (NC - c0 < 16) ? (NC - c0) : 16;

  // cooperative Y tile load: 4096 elems, 256 threads -> 16 each
  for (int i = threadIdx.x; i < (NS / KC_GEMM) * 16; i += 256) {
    int r = i >> 4, cc = i & 15;
    ytile[r][cc] = (cc < cmax) ? Y[(size_t)(n0 + r) * NC + c0 + cc] : 0.f;
  }
  __syncthreads();

  float acc[16];
  #pragma unroll
  for (int j = 0; j < 16; ++j) acc[j] = 0.f;

  #pragma unroll 4
  for (int n = 0; n < NS / KC_GEMM; ++n) {
    float xv = X[(size_t)(n0 + n) * NF + f];
    #pragma unroll
    for (int j = 0; j < 16; ++j) acc[j] = fmaf(ytile[n][j], xv, acc[j]);
  }

  #pragma unroll
  for (int j = 0; j < 16; ++j)
    if (c0 + j < NC) P[((size_t)kc * NC + c0 + j) * NF + f] = acc[j];
}

// ---------------- kernel 3: column-sum partials ----------------
__global__ void k_colsum(const float* __restrict__ Y, float* __restrict__ CS) {
  int c  = threadIdx.x;                 // 512 threads
  int kc = blockIdx.x;                  // 32 chunks of 128 rows
  float s = 0.f;
  if (c < NC) {
    int n0 = kc * (NS / KC_CS);
    for (int n = n0; n < n0 + NS / KC_CS; ++n) s += Y[(size_t)n * NC + c];
  }
  CS[kc * 512 + c] = s;
}

// ---------------- kernel 4: finalize means ----------------
__global__ void k_means(const float* __restrict__ qsum,
                        const int* __restrict__ qsize,
                        const float* __restrict__ Psrc,
                        const float* __restrict__ Ptgt,
                        const float* __restrict__ CSsrc,
                        const float* __restrict__ CStgt,
                        float* __restrict__ MS, float* __restrict__ MT) {
  int c = blockIdx.x, f = threadIdx.x;
  float cs_s = 0.f, cs_t = 0.f;
  #pragma unroll
  for (int kc = 0; kc < KC_CS; ++kc) {
    cs_s += CSsrc[kc * 512 + c];
    cs_t += CStgt[kc * 512 + c];
  }
  float num = (float)qsize[c];
  float ns = qsum[(size_t)c * NF + f];
  float nt = 0.f;
  #pragma unroll
  for (int kc = 0; kc < KC_GEMM; ++kc) {
    ns += Psrc[((size_t)kc * NC + c) * NF + f];
    nt += Ptgt[((size_t)kc * NC + c) * NF + f];
  }
  MS[(size_t)c * NF + f] = ns / (num + cs_s + 1e-8f);
  MT[(size_t)c * NF + f] = nt / (cs_t + 1e-8f);
}

// ---------------- kernel 5: distances ----------------
__global__ void k_dist(const float* __restrict__ MS, const float* __restrict__ MT,
                       float* __restrict__ ipart, float* __restrict__ epart) {
  int c1 = blockIdx.x, f = threadIdx.x;  // 256 threads
  __shared__ float a[NF];
  __shared__ float red[8];
  float av = MS[(size_t)c1 * NF + f];
  a[f] = av;
  float d = av - MT[(size_t)c1 * NF + f];
  float s = d * d;
  #pragma unroll
  for (int m = 32; m; m >>= 1) s += __shfl_xor(s, m);
  int wid = f >> 6, lane = f & 63;
  if (lane == 0) red[wid] = s;
  __syncthreads();
  if (f == 0) ipart[c1] = sqrtf(fmaxf(red[0] + red[1] + red[2] + red[3], 1e-12f));

  float wsum = 0.f;
  for (int c2 = wid; c2 < NC; c2 += 4) {
    float t = 0.f;
    #pragma unroll
    for (int j = 0; j < 4; ++j) {
      int ff = lane + 64 * j;
      float dd = a[ff] - MS[(size_t)c2 * NF + ff];
      t = fmaf(dd, dd, t);
    }
    #pragma unroll
    for (int m = 32; m; m >>= 1) t += __shfl_xor(t, m);
    if (lane == 0) wsum += sqrtf(fmaxf(t, 1e-12f));
  }
  if (lane == 0) red[4 + wid] = wsum;
  __syncthreads();
  if (f == 0) epart[c1] = red[4] + red[5] + red[6] + red[7];
}

// ---------------- kernel 6: final scalars ----------------
__global__ void k_final(const float* __restrict__ ipart,
                        const float* __restrict__ epart,
                        float* __restrict__ out) {
  int t = threadIdx.x;                  // 512 threads
  float si = 0.f, se = 0.f;
  if (t < NC) { si = ipart[t]; se = epart[t]; }
  #pragma unroll
  for (int m = 32; m; m >>= 1) { si += __shfl_xor(si, m); se += __shfl_xor(se, m); }
  __shared__ float ri[8], re[8];
  int wid = t >> 6, lane = t & 63;
  if (lane == 0) { ri[wid] = si; re[wid] = se; }
  __syncthreads();
  if (t == 0) {
    float A = 0.f, B = 0.f;
    #pragma unroll
    for (int w = 0; w < 8; ++w) { A += ri[w]; B += re[w]; }
    out[0] = A / (float)NC;
    out[1] = B / ((float)NC * (float)NC);
  }
}

extern "C" void kernel_launch(void* const* d_in, const int* in_sizes, int n_in,
                              void* d_out, int out_size, void* d_ws, size_t ws_size,
                              hipStream_t stream) {
  const float* src_x = (const float*)d_in[0];
  const float* tgt_x = (const float*)d_in[1];
  const float* src_y = (const float*)d_in[2];
  const float* tgt_y = (const float*)d_in[3];
  const float* queue = (const float*)d_in[4];
  const int*   qsize = (const int*)d_in[5];
  float* out = (float*)d_out;

  float* ws   = (float*)d_ws;
  float* qsum = ws;                                   // 128000
  float* Psrc = qsum + NC * NF;                       // 16 * 128000
  float* Ptgt = Psrc + (size_t)KC_GEMM * NC * NF;     // 16 * 128000
  float* CSs  = Ptgt + (size_t)KC_GEMM * NC * NF;     // 32 * 512
  float* CSt  = CSs + KC_CS * 512;                    // 32 * 512
  float* MS   = CSt + KC_CS * 512;                    // 128000
  float* MT   = MS + NC * NF;                         // 128000
  float* ipart = MT + NC * NF;                        // 500
  float* epart = ipart + NC;                          // 500

  // 1) queue masked sums: 128000 waves, 4 waves/block
  k_queue_reduce<<<(NC * NF) / 4, 256, 0, stream>>>(queue, qsize, qsum);

  // 2) GEMM partials, src+tgt fused (deterministic split-K)
  dim3 g2((NC + 15) / 16, KC_GEMM, 2);
  k_gemm_partial<<<g2, 256, 0, stream>>>(src_x, src_y, Psrc, tgt_x, tgt_y, Ptgt);

  // 3) column sums
  k_colsum<<<KC_CS, 512, 0, stream>>>(src_y, CSs);
  k_colsum<<<KC_CS, 512, 0, stream>>>(tgt_y, CSt);

  // 4) means
  k_means<<<NC, NF, 0, stream>>>(qsum, qsize, Psrc, Ptgt, CSs, CSt, MS, MT);

  // 5) distances
  k_dist<<<NC, NF, 0, stream>>>(MS, MT, ipart, epart);

  // 6) final reduction
  k_final<<<1, 512, 0, stream>>>(ipart, epart, out);
}

// Round 3
// 91.464 us; speedup vs baseline: 5.8753x; 1.8193x over previous
//
#include <hip/hip_runtime.h>
#include <math.h>

#define NS 4096
#define NC 500
#define NF 256
#define NK 400
#define KC_GEMM 16     // K chunks for gemm split (256 rows each)
#define KC_CS   32     // K chunks for colsum (128 rows each)

#define NB_GEMM (32 * KC_GEMM * 2)        // 1024 blocks
#define NB_CS   (KC_CS * 2)               // 64 blocks
#define NB_QUE  ((NC * NF) / 4)           // 32000 blocks (4 waves each)

// ---------------- kernel 1: fused heavy pass ----------------
// blockIdx regions: [0,1024) gemm | [1024,1088) colsum | [1088,33088) queue
// The three jobs stress different pipes (VALU+LDS / latency / HBM) and overlap.
__global__ __launch_bounds__(256) void k_heavy(
    const float* __restrict__ Xs, const float* __restrict__ Ys, float* __restrict__ Ps,
    const float* __restrict__ Xt, const float* __restrict__ Yt, float* __restrict__ Pt,
    float* __restrict__ CSs, float* __restrict__ CSt,
    const float* __restrict__ queue, const int* __restrict__ qsize,
    float* __restrict__ qsum) {
  __shared__ float ytile[NS / KC_GEMM][16];     // 16 KB (gemm blocks only)
  const int bid = blockIdx.x;

  if (bid < NB_GEMM) {
    // ---- GEMM partials: P[kc][c][f] = sum_{n in chunk} Y[n,c] * X[n,f]
    const int z   = bid >> 9;                   // 0:src 1:tgt
    const int rem = bid & 511;
    const int kc  = rem >> 5;
    const int c0  = (rem & 31) * 16;
    const float* X = z ? Xt : Xs;
    const float* Y = z ? Yt : Ys;
    float*       P = z ? Pt : Ps;
    const int n0   = kc * (NS / KC_GEMM);
    const int cmax = (NC - c0 < 16) ? (NC - c0) : 16;

    for (int i = threadIdx.x; i < (NS / KC_GEMM) * 16; i += 256) {
      int r = i >> 4, cc = i & 15;
      ytile[r][cc] = (cc < cmax) ? Y[(size_t)(n0 + r) * NC + c0 + cc] : 0.f;
    }
    __syncthreads();

    const int f = threadIdx.x;
    float acc[16];
    #pragma unroll
    for (int j = 0; j < 16; ++j) acc[j] = 0.f;

    #pragma unroll 4
    for (int n = 0; n < NS / KC_GEMM; ++n) {
      float xv = X[(size_t)(n0 + n) * NF + f];
      #pragma unroll
      for (int j = 0; j < 16; ++j) acc[j] = fmaf(ytile[n][j], xv, acc[j]);
    }
    #pragma unroll
    for (int j = 0; j < 16; ++j)
      if (c0 + j < NC) P[((size_t)kc * NC + c0 + j) * NF + f] = acc[j];

  } else if (bid < NB_GEMM + NB_CS) {
    // ---- column sums: CS[kc][c] = sum_{n in chunk} Y[n,c]
    const int b = bid - NB_GEMM;
    const float* Y = (b >> 5) ? Yt : Ys;
    float*      CS = (b >> 5) ? CSt : CSs;
    const int kc = b & 31;
    const int n0 = kc * (NS / KC_CS);
    const int t  = threadIdx.x;
    float s0 = 0.f, s1 = 0.f;
    for (int n = n0; n < n0 + NS / KC_CS; ++n) {
      const float* row = Y + (size_t)n * NC;
      s0 += row[t];
      if (t + 256 < NC) s1 += row[t + 256];
    }
    CS[kc * 512 + t] = s0;
    if (t + 256 < NC) CS[kc * 512 + t + 256] = s1;

  } else {
    // ---- masked queue reduction: one wave per (c,f) row of 400 floats
    const int qb   = bid - (NB_GEMM + NB_CS);
    const int wave = qb * 4 + (threadIdx.x >> 6);
    const int lane = threadIdx.x & 63;
    const int c    = wave >> 8;                 // NF = 256
    const int qs   = qsize[c];
    const float* base = queue + (size_t)wave * NK;
    float s = 0.f;
    {
      int k = 4 * lane;                         // 0..255
      float4 v = *reinterpret_cast<const float4*>(base + k);
      if (k + 0 < qs) s += v.x;
      if (k + 1 < qs) s += v.y;
      if (k + 2 < qs) s += v.z;
      if (k + 3 < qs) s += v.w;
    }
    if (lane < 36) {
      int k = 256 + 4 * lane;                   // 256..399
      float4 v = *reinterpret_cast<const float4*>(base + k);
      if (k + 0 < qs) s += v.x;
      if (k + 1 < qs) s += v.y;
      if (k + 2 < qs) s += v.z;
      if (k + 3 < qs) s += v.w;
    }
    #pragma unroll
    for (int m = 32; m; m >>= 1) s += __shfl_xor(s, m);
    if (lane == 0) qsum[wave] = s;
  }
}

// ---------------- kernel 2: finalize means + intra diagonal ----------------
__global__ __launch_bounds__(256) void k_means(
    const float* __restrict__ qsum, const int* __restrict__ qsize,
    const float* __restrict__ Psrc, const float* __restrict__ Ptgt,
    const float* __restrict__ CSsrc, const float* __restrict__ CStgt,
    float* __restrict__ MS, float* __restrict__ MT, float* __restrict__ ipart) {
  const int c = blockIdx.x, f = threadIdx.x;
  float cs_s = 0.f, cs_t = 0.f;
  #pragma unroll
  for (int kc = 0; kc < KC_CS; ++kc) {
    cs_s += CSsrc[kc * 512 + c];
    cs_t += CStgt[kc * 512 + c];
  }
  float num = (float)qsize[c];
  float ns = qsum[(size_t)c * NF + f];
  float nt = 0.f;
  #pragma unroll
  for (int kc = 0; kc < KC_GEMM; ++kc) {
    ns += Psrc[((size_t)kc * NC + c) * NF + f];
    nt += Ptgt[((size_t)kc * NC + c) * NF + f];
  }
  float ms = ns / (num + cs_s + 1e-8f);
  float mt = nt / (cs_t + 1e-8f);
  MS[(size_t)c * NF + f] = ms;
  MT[(size_t)c * NF + f] = mt;

  // intra diagonal: ||ms - mt|| over the 256 features of this block
  float d = ms - mt;
  float s = d * d;
  #pragma unroll
  for (int m = 32; m; m >>= 1) s += __shfl_xor(s, m);
  __shared__ float red[4];
  int wid = f >> 6, lane = f & 63;
  if (lane == 0) red[wid] = s;
  __syncthreads();
  if (f == 0) ipart[c] = sqrtf(fmaxf(red[0] + red[1] + red[2] + red[3], 1e-12f));
}

// ---------------- kernel 3: pairwise distances (16x16 tiles) ----------------
#define TC 16
#define NBT 32                              // ceil(500/16)
__global__ __launch_bounds__(256) void k_dist(const float* __restrict__ MS,
                                              float* __restrict__ epart) {
  __shared__ float a[TC][NF + 4];           // +4 pad: 2-way max bank aliasing
  __shared__ float b[TC][NF + 4];
  const int bi = blockIdx.x & (NBT - 1);
  const int bj = blockIdx.x >> 5;

  for (int i = threadIdx.x; i < TC * (NF / 4); i += 256) {
    int r = i >> 6, fq = (i & 63) * 4;      // NF/4 = 64
    int c1 = bi * TC + r;
    int c2 = bj * TC + r;
    float4 va = (c1 < NC) ? *reinterpret_cast<const float4*>(&MS[(size_t)c1 * NF + fq])
                          : make_float4(0.f, 0.f, 0.f, 0.f);
    float4 vb = (c2 < NC) ? *reinterpret_cast<const float4*>(&MS[(size_t)c2 * NF + fq])
                          : make_float4(0.f, 0.f, 0.f, 0.f);
    *reinterpret_cast<float4*>(&a[r][fq]) = va;
    *reinterpret_cast<float4*>(&b[r][fq]) = vb;
  }
  __syncthreads();

  const int i1 = threadIdx.x >> 4, i2 = threadIdx.x & 15;
  float s = 0.f;
  #pragma unroll 8
  for (int fq = 0; fq < NF; fq += 4) {
    float4 va = *reinterpret_cast<const float4*>(&a[i1][fq]);
    float4 vb = *reinterpret_cast<const float4*>(&b[i2][fq]);
    float d0 = va.x - vb.x, d1 = va.y - vb.y, d2 = va.z - vb.z, d3 = va.w - vb.w;
    s = fmaf(d0, d0, s); s = fmaf(d1, d1, s); s = fmaf(d2, d2, s); s = fmaf(d3, d3, s);
  }
  bool valid = (bi * TC + i1 < NC) && (bj * TC + i2 < NC);
  float r = valid ? sqrtf(fmaxf(s, 1e-12f)) : 0.f;

  // block reduce 256 values
  #pragma unroll
  for (int m = 32; m; m >>= 1) r += __shfl_xor(r, m);
  __shared__ float red[4];
  int wid = threadIdx.x >> 6, lane = threadIdx.x & 63;
  if (lane == 0) red[wid] = r;
  __syncthreads();
  if (threadIdx.x == 0) epart[blockIdx.x] = red[0] + red[1] + red[2] + red[3];
}

// ---------------- kernel 4: final scalars ----------------
__global__ __launch_bounds__(1024) void k_final(const float* __restrict__ ipart,
                                                const float* __restrict__ epart,
                                                float* __restrict__ out) {
  const int t = threadIdx.x;                // 1024 threads
  float si = (t < NC) ? ipart[t] : 0.f;
  float se = epart[t];
  #pragma unroll
  for (int m = 32; m; m >>= 1) { si += __shfl_xor(si, m); se += __shfl_xor(se, m); }
  __shared__ float ri[16], re[16];
  int wid = t >> 6, lane = t & 63;
  if (lane == 0) { ri[wid] = si; re[wid] = se; }
  __syncthreads();
  if (t == 0) {
    float A = 0.f, B = 0.f;
    #pragma unroll
    for (int w = 0; w < 16; ++w) { A += ri[w]; B += re[w]; }
    out[0] = A / (float)NC;
    out[1] = B / ((float)NC * (float)NC);
  }
}

extern "C" void kernel_launch(void* const* d_in, const int* in_sizes, int n_in,
                              void* d_out, int out_size, void* d_ws, size_t ws_size,
                              hipStream_t stream) {
  const float* src_x = (const float*)d_in[0];
  const float* tgt_x = (const float*)d_in[1];
  const float* src_y = (const float*)d_in[2];
  const float* tgt_y = (const float*)d_in[3];
  const float* queue = (const float*)d_in[4];
  const int*   qsize = (const int*)d_in[5];
  float* out = (float*)d_out;

  float* ws    = (float*)d_ws;
  float* qsum  = ws;                                   // 128000
  float* Psrc  = qsum + NC * NF;                       // 16 * 128000
  float* Ptgt  = Psrc + (size_t)KC_GEMM * NC * NF;     // 16 * 128000
  float* CSs   = Ptgt + (size_t)KC_GEMM * NC * NF;     // 32 * 512
  float* CSt   = CSs + KC_CS * 512;                    // 32 * 512
  float* MS    = CSt + KC_CS * 512;                    // 128000
  float* MT    = MS + NC * NF;                         // 128000
  float* ipart = MT + NC * NF;                         // 500
  float* epart = ipart + NC;                           // 1024

  // 1) fused heavy pass: gemm + colsum + queue reduction
  k_heavy<<<NB_GEMM + NB_CS + NB_QUE, 256, 0, stream>>>(
      src_x, src_y, Psrc, tgt_x, tgt_y, Ptgt, CSs, CSt, queue, qsize, qsum);

  // 2) means + intra diagonal
  k_means<<<NC, 256, 0, stream>>>(qsum, qsize, Psrc, Ptgt, CSs, CSt, MS, MT, ipart);

  // 3) pairwise distances
  k_dist<<<NBT * NBT, 256, 0, stream>>>(MS, epart);

  // 4) final reduction
  k_final<<<1, 1024, 0, stream>>>(ipart, epart, out);
}